// Round 1
// baseline (5786.274 us; speedup 1.0000x reference)
//
#include <hip/hip_runtime.h>

// ---------------------------------------------------------------------------
// EdgeGatedConv fp32 baseline.
// Pipeline:
//   memset: out_x (agg_atom accumulator), out_lg (lg segment-sum accumulator), cnt
//   K1 k_line_msg:   msg = silu([lg_x[src],lg_x[dst],lg_ea] @ W_line + b); atomic-> out_lg[dst], cnt[dst]
//   K2 k_lg_final:   out_lg = lg_x + out_lg/max(cnt,1); out_edge = LN(edge_attr + out_lg)
//   K3 k_gate:       gate = sigmoid(out_edge @ W_gate + b); atomic gate*out_edge -> out_x[col]
//   K4 k_atom:       h = silu([x, out_x] @ W_atom + b); out_x = LN(x + h)
// ---------------------------------------------------------------------------

__global__ __launch_bounds__(256) void k_line_msg(
    const float* __restrict__ lg_x, const float* __restrict__ lg_ea,
    const float* __restrict__ W, const float* __restrict__ b,
    const int* __restrict__ lg_src, const int* __restrict__ lg_dst,
    float* __restrict__ lgacc, float* __restrict__ cnt, int LEn)
{
    __shared__ float At[32][256];   // 32 KB gathered A tile
    __shared__ float Wt[64][128];   // 32 KB W k-tile
    const int tid = threadIdx.x;
    const int e0 = blockIdx.x * 32;

    // gather A: per edge, row = [lg_x[src] (128) | lg_x[dst] (128)]
    #pragma unroll
    for (int i = 0; i < 8; ++i) {
        int c = tid + i * 256;          // float4 chunk id: 32 edges * 64 chunks
        int e = c >> 6, q = c & 63;
        int le = e0 + e;
        float4 v = make_float4(0.f, 0.f, 0.f, 0.f);
        if (le < LEn) {
            int node = (q < 32) ? lg_src[le] : lg_dst[le];
            v = ((const float4*)(lg_x + (size_t)node * 128))[q & 31];
        }
        *(float4*)&At[e][q * 4] = v;
    }

    float acc[16];
    #pragma unroll
    for (int i = 0; i < 16; ++i) acc[i] = 0.f;
    const int j = tid & 127;    // output column
    const int h = tid >> 7;     // edge half: 16 edges each

    for (int kt = 0; kt < 4; ++kt) {
        __syncthreads();
        #pragma unroll
        for (int i = 0; i < 8; ++i) {
            int c = tid + i * 256;      // 64x128 floats = 2048 float4
            int kk = c >> 5, q = c & 31;
            *(float4*)&Wt[kk][q * 4] =
                *(const float4*)&W[(size_t)(kt * 64 + kk) * 128 + q * 4];
        }
        __syncthreads();
        #pragma unroll
        for (int kk = 0; kk < 64; kk += 4) {
            float w0 = Wt[kk + 0][j];
            float w1 = Wt[kk + 1][j];
            float w2 = Wt[kk + 2][j];
            float w3 = Wt[kk + 3][j];
            #pragma unroll
            for (int e = 0; e < 16; ++e) {
                float4 a = *(const float4*)&At[h * 16 + e][kt * 64 + kk];
                acc[e] = fmaf(a.w, w3, fmaf(a.z, w2, fmaf(a.y, w1, fmaf(a.x, w0, acc[e]))));
            }
        }
    }

    const float wlast = W[(size_t)256 * 128 + j];   // K=256 row: lg_edge_attr scalar
    const float bias = b[j];
    #pragma unroll
    for (int e = 0; e < 16; ++e) {
        int le = e0 + h * 16 + e;
        if (le >= LEn) break;
        float v = fmaf(lg_ea[le], wlast, acc[e] + bias);
        float s = v / (1.f + __expf(-v));           // silu
        atomicAdd(&lgacc[(size_t)lg_dst[le] * 128 + j], s);
    }
    if (j == 0) {
        #pragma unroll
        for (int e = 0; e < 16; ++e) {
            int le = e0 + h * 16 + e;
            if (le < LEn) atomicAdd(&cnt[lg_dst[le]], 1.f);
        }
    }
}

__global__ __launch_bounds__(256) void k_lg_final_edge_ln(
    const float* __restrict__ lg_x, const float* __restrict__ edge_attr,
    const float* __restrict__ cnt,
    const float* __restrict__ g_edge, const float* __restrict__ beta_edge,
    float* __restrict__ out_lg, float* __restrict__ out_edge, int En)
{
    const int wave = threadIdx.x >> 6;
    const int lane = threadIdx.x & 63;
    const int e = blockIdx.x * 4 + wave;
    if (e >= En) return;
    const size_t base = (size_t)e * 128 + lane * 2;
    float2 accv = *(const float2*)&out_lg[base];
    float2 lgv  = *(const float2*)&lg_x[base];
    float inv = 1.f / fmaxf(cnt[e], 1.f);
    float2 lnew = make_float2(fmaf(accv.x, inv, lgv.x), fmaf(accv.y, inv, lgv.y));
    *(float2*)&out_lg[base] = lnew;
    float2 ea = *(const float2*)&edge_attr[base];
    float t0 = ea.x + lnew.x, t1 = ea.y + lnew.y;
    float s = t0 + t1, sq = t0 * t0 + t1 * t1;
    #pragma unroll
    for (int off = 32; off; off >>= 1) {
        s  += __shfl_xor(s, off);
        sq += __shfl_xor(sq, off);
    }
    float mean = s * (1.f / 128.f);
    float var  = sq * (1.f / 128.f) - mean * mean;
    float r = rsqrtf(var + 1e-5f);
    int j0 = lane * 2;
    float o0 = (t0 - mean) * r * g_edge[j0]     + beta_edge[j0];
    float o1 = (t1 - mean) * r * g_edge[j0 + 1] + beta_edge[j0 + 1];
    *(float2*)&out_edge[base] = make_float2(o0, o1);
}

__global__ __launch_bounds__(256) void k_gate_scatter(
    const float* __restrict__ edge_new, const float* __restrict__ Wg,
    const float* __restrict__ bg, const int* __restrict__ col,
    float* __restrict__ agg, int En)
{
    __shared__ float At[32][128];    // 16 KB
    __shared__ float Wt[128][128];   // 64 KB (full W_gate)
    const int tid = threadIdx.x;
    const int e0 = blockIdx.x * 32;

    #pragma unroll
    for (int i = 0; i < 4; ++i) {
        int c = tid + i * 256;
        int e = c >> 5, q = c & 31;
        int ee = e0 + e;
        float4 v = make_float4(0.f, 0.f, 0.f, 0.f);
        if (ee < En) v = *(const float4*)&edge_new[(size_t)ee * 128 + q * 4];
        *(float4*)&At[e][q * 4] = v;
    }
    #pragma unroll
    for (int i = 0; i < 16; ++i) {
        int c = tid + i * 256;
        int kk = c >> 5, q = c & 31;
        *(float4*)&Wt[kk][q * 4] = *(const float4*)&Wg[(size_t)kk * 128 + q * 4];
    }
    __syncthreads();

    const int j = tid & 127, h = tid >> 7;
    float acc[16];
    #pragma unroll
    for (int i = 0; i < 16; ++i) acc[i] = 0.f;
    #pragma unroll
    for (int kk = 0; kk < 128; kk += 4) {
        float w0 = Wt[kk][j], w1 = Wt[kk + 1][j], w2 = Wt[kk + 2][j], w3 = Wt[kk + 3][j];
        #pragma unroll
        for (int e = 0; e < 16; ++e) {
            float4 a = *(const float4*)&At[h * 16 + e][kk];
            acc[e] = fmaf(a.w, w3, fmaf(a.z, w2, fmaf(a.y, w1, fmaf(a.x, w0, acc[e]))));
        }
    }
    const float bias = bg[j];
    #pragma unroll
    for (int e = 0; e < 16; ++e) {
        int ee = e0 + h * 16 + e;
        if (ee >= En) break;
        float g = 1.f / (1.f + __expf(-(acc[e] + bias)));
        float val = g * At[h * 16 + e][j];
        atomicAdd(&agg[(size_t)col[ee] * 128 + j], val);
    }
}

__global__ __launch_bounds__(256) void k_atom(
    const float* __restrict__ x, const float* __restrict__ Wa,
    const float* __restrict__ ba, const float* __restrict__ g_node,
    const float* __restrict__ beta_node,
    float* __restrict__ out_x, int Nn)
{
    __shared__ float At[32][256];  // 32 KB: [x | agg]
    __shared__ float Wt[64][128];  // 32 KB
    __shared__ float Tt[32][128];  // 16 KB: pre-LN values
    const int tid = threadIdx.x;
    const int n0 = blockIdx.x * 32;

    #pragma unroll
    for (int i = 0; i < 8; ++i) {
        int c = tid + i * 256;
        int e = c >> 6, q = c & 63;
        int n = n0 + e;
        float4 v = make_float4(0.f, 0.f, 0.f, 0.f);
        if (n < Nn) {
            v = (q < 32) ? ((const float4*)(x     + (size_t)n * 128))[q]
                         : ((const float4*)(out_x + (size_t)n * 128))[q - 32];
        }
        *(float4*)&At[e][q * 4] = v;
    }

    const int j = tid & 127, h = tid >> 7;
    float acc[16];
    #pragma unroll
    for (int i = 0; i < 16; ++i) acc[i] = 0.f;

    for (int kt = 0; kt < 4; ++kt) {
        __syncthreads();
        #pragma unroll
        for (int i = 0; i < 8; ++i) {
            int c = tid + i * 256;
            int kk = c >> 5, q = c & 31;
            *(float4*)&Wt[kk][q * 4] =
                *(const float4*)&Wa[(size_t)(kt * 64 + kk) * 128 + q * 4];
        }
        __syncthreads();
        #pragma unroll
        for (int kk = 0; kk < 64; kk += 4) {
            float w0 = Wt[kk][j], w1 = Wt[kk + 1][j], w2 = Wt[kk + 2][j], w3 = Wt[kk + 3][j];
            #pragma unroll
            for (int e = 0; e < 16; ++e) {
                float4 a = *(const float4*)&At[h * 16 + e][kt * 64 + kk];
                acc[e] = fmaf(a.w, w3, fmaf(a.z, w2, fmaf(a.y, w1, fmaf(a.x, w0, acc[e]))));
            }
        }
    }
    const float bias = ba[j];
    #pragma unroll
    for (int e = 0; e < 16; ++e) {
        float v = acc[e] + bias;
        float hs = v / (1.f + __expf(-v));
        Tt[h * 16 + e][j] = At[h * 16 + e][j] + hs;   // x + h  (j < 128 -> x half)
    }
    __syncthreads();

    const int wave = tid >> 6, lane = tid & 63;
    #pragma unroll
    for (int r = 0; r < 8; ++r) {
        int e = wave * 8 + r;
        int n = n0 + e;
        if (n >= Nn) continue;
        float t0 = Tt[e][lane * 2], t1 = Tt[e][lane * 2 + 1];
        float s = t0 + t1, sq = t0 * t0 + t1 * t1;
        #pragma unroll
        for (int off = 32; off; off >>= 1) {
            s  += __shfl_xor(s, off);
            sq += __shfl_xor(sq, off);
        }
        float mean = s * (1.f / 128.f);
        float var  = sq * (1.f / 128.f) - mean * mean;
        float rr = rsqrtf(var + 1e-5f);
        int j0 = lane * 2;
        float o0 = (t0 - mean) * rr * g_node[j0]     + beta_node[j0];
        float o1 = (t1 - mean) * rr * g_node[j0 + 1] + beta_node[j0 + 1];
        *(float2*)&out_x[(size_t)n * 128 + j0] = make_float2(o0, o1);
    }
}

extern "C" void kernel_launch(void* const* d_in, const int* in_sizes, int n_in,
                              void* d_out, int out_size, void* d_ws, size_t ws_size,
                              hipStream_t stream) {
    const float* x          = (const float*)d_in[0];
    const float* edge_attr  = (const float*)d_in[1];
    const float* lg_x       = (const float*)d_in[2];
    const float* lg_ea      = (const float*)d_in[3];
    const float* W_line     = (const float*)d_in[4];
    const float* b_line     = (const float*)d_in[5];
    const float* W_gate     = (const float*)d_in[6];
    const float* b_gate     = (const float*)d_in[7];
    const float* W_atom     = (const float*)d_in[8];
    const float* b_atom     = (const float*)d_in[9];
    const float* g_node     = (const float*)d_in[10];
    const float* beta_node  = (const float*)d_in[11];
    const float* g_edge     = (const float*)d_in[12];
    const float* beta_edge  = (const float*)d_in[13];
    const int*   edge_index    = (const int*)d_in[14];
    const int*   lg_edge_index = (const int*)d_in[15];

    const int Nn  = in_sizes[0] / 128;   // 200000
    const int En  = in_sizes[1] / 128;   // 1000000 (line-graph node count == E)
    const int LEn = in_sizes[3];         // 1000000 line-graph edges

    float* out_x    = (float*)d_out;                    // [N,128]  (holds atom agg first)
    float* out_edge = out_x + (size_t)Nn * 128;         // [E,128]
    float* out_lg   = out_edge + (size_t)En * 128;      // [E,128]  (holds lg segment-sum first)
    float* cnt      = (float*)d_ws;                     // [E]

    const int* lg_src = lg_edge_index;
    const int* lg_dst = lg_edge_index + LEn;
    const int* col    = edge_index + En;                // edge_index[1]

    hipMemsetAsync(out_x,  0, (size_t)Nn * 128 * sizeof(float), stream);
    hipMemsetAsync(out_lg, 0, (size_t)En * 128 * sizeof(float), stream);
    hipMemsetAsync(cnt,    0, (size_t)En * sizeof(float), stream);

    k_line_msg<<<(LEn + 31) / 32, 256, 0, stream>>>(
        lg_x, lg_ea, W_line, b_line, lg_src, lg_dst, out_lg, cnt, LEn);
    k_lg_final_edge_ln<<<(En + 3) / 4, 256, 0, stream>>>(
        lg_x, edge_attr, cnt, g_edge, beta_edge, out_lg, out_edge, En);
    k_gate_scatter<<<(En + 31) / 32, 256, 0, stream>>>(
        out_edge, W_gate, b_gate, col, out_x, En);
    k_atom<<<(Nn + 31) / 32, 256, 0, stream>>>(
        x, W_atom, b_atom, g_node, beta_node, out_x, Nn);
}

// Round 2
// 2258.044 us; speedup vs baseline: 2.5625x; 2.5625x over previous
//
#include <hip/hip_runtime.h>

// ---------------------------------------------------------------------------
// EdgeGatedConv — bf16 MFMA version.
//   prep: pack W_line/W_gate/W_atom to bf16 fragment-ready layout in d_ws
//   K0 k_count:    cnt[dst]++ (scatter-mean denominator)
//   K1 k_line_mfma: msg = silu([lg_x[src],lg_x[dst],lg_ea]@W_line+b) -> atomic out_lg[dst]
//   K2 k_lg_final:  out_lg = lg_x + out_lg/max(cnt,1); out_edge = LN(edge_attr+out_lg)
//   K3 k_gate_mfma: gate=sigmoid(out_edge@W_gate+b); atomic gate*out_edge -> out_x[col]
//   K4 k_atom_mfma: h=silu([x,agg]@W_atom+b); out_x = LN(x+h)  (LN in-register)
//
// MFMA 16x16x32 bf16 fragments: A row = lane&15, B col = lane&15,
// k-slice = (lane>>4)*8 + j on BOTH A and B (consistent bijection -> correct
// for any hw k-permutation). C/D: col = lane&15, row = (lane>>4)*4 + reg.
// ---------------------------------------------------------------------------

typedef __attribute__((ext_vector_type(8))) short s16x8;
typedef __attribute__((ext_vector_type(4))) float f32x4;

__device__ __forceinline__ short f2bf(float f) {
    unsigned u = __float_as_uint(f);
    u += 0x7FFF + ((u >> 16) & 1);           // round-to-nearest-even
    return (short)(u >> 16);
}

__device__ __forceinline__ s16x8 pack8(float4 a, float4 b) {
    s16x8 r;
    r[0] = f2bf(a.x); r[1] = f2bf(a.y); r[2] = f2bf(a.z); r[3] = f2bf(a.w);
    r[4] = f2bf(b.x); r[5] = f2bf(b.y); r[6] = f2bf(b.z); r[7] = f2bf(b.w);
    return r;
}

// pack W[K][128] -> P chunks: chunk c = g*128+col (g = k/8), holds W[g*8+j][col], j=0..7
__global__ __launch_bounds__(256) void k_pack(const float* __restrict__ W,
                                              short* __restrict__ P, int nchunk) {
    int c = blockIdx.x * 256 + threadIdx.x;
    if (c >= nchunk) return;
    int g = c >> 7, col = c & 127, k0 = g * 8;
    s16x8 v;
    #pragma unroll
    for (int j = 0; j < 8; ++j) v[j] = f2bf(W[(size_t)(k0 + j) * 128 + col]);
    ((s16x8*)P)[c] = v;
}

__global__ __launch_bounds__(256) void k_count(const int* __restrict__ dst,
                                               float* __restrict__ cnt, int n) {
    int i = blockIdx.x * 256 + threadIdx.x;
    if (i < n) atomicAdd(&cnt[dst[i]], 1.f);
}

// ---------------- K1: line-graph message GEMM + scatter ----------------
__global__ __launch_bounds__(256) void k_line_mfma(
    const float* __restrict__ lg_x, const float* __restrict__ lg_ea,
    const short* __restrict__ Wp, const float* __restrict__ W_line,
    const float* __restrict__ b_line,
    const int* __restrict__ lg_src, const int* __restrict__ lg_dst,
    float* __restrict__ lgacc, int LEn)
{
    __shared__ s16x8 B[4096];                 // 64 KB: [g=kt*4+lhi(32)][col(128)]
    const int tid = threadIdx.x;
    #pragma unroll
    for (int i = 0; i < 16; ++i)
        ((float4*)B)[tid + i * 256] = ((const float4*)Wp)[tid + i * 256];
    __syncthreads();

    const int ln = tid & 63, wv = tid >> 6;
    const int l15 = ln & 15, lhi = ln >> 4;
    const int eb = blockIdx.x * 128 + wv * 32;

    const float *sp[2], *dp[2];
    #pragma unroll
    for (int mt = 0; mt < 2; ++mt) {
        int e = eb + mt * 16 + l15;
        int ec = e < LEn ? e : LEn - 1;
        sp[mt] = lg_x + (size_t)lg_src[ec] * 128;
        dp[mt] = lg_x + (size_t)lg_dst[ec] * 128;
    }

    f32x4 acc[2][8];
    #pragma unroll
    for (int m = 0; m < 2; ++m)
        #pragma unroll
        for (int n = 0; n < 8; ++n) acc[m][n] = (f32x4){0.f, 0.f, 0.f, 0.f};

    #pragma unroll 2
    for (int kt = 0; kt < 8; ++kt) {
        int ko = (kt & 3) * 32 + lhi * 8;
        s16x8 a[2];
        #pragma unroll
        for (int mt = 0; mt < 2; ++mt) {
            const float* p = (kt < 4) ? sp[mt] : dp[mt];
            float4 u0 = *(const float4*)(p + ko);
            float4 u1 = *(const float4*)(p + ko + 4);
            a[mt] = pack8(u0, u1);
        }
        const s16x8* brow = &B[(kt * 4 + lhi) * 128 + l15];
        #pragma unroll
        for (int nt = 0; nt < 8; ++nt) {
            s16x8 b = brow[nt * 16];
            acc[0][nt] = __builtin_amdgcn_mfma_f32_16x16x32_bf16(a[0], b, acc[0][nt], 0, 0, 0);
            acc[1][nt] = __builtin_amdgcn_mfma_f32_16x16x32_bf16(a[1], b, acc[1][nt], 0, 0, 0);
        }
    }

    #pragma unroll
    for (int nt = 0; nt < 8; ++nt) {
        int col = nt * 16 + l15;
        float wl = W_line[(size_t)256 * 128 + col];
        float bs = b_line[col];
        #pragma unroll
        for (int mt = 0; mt < 2; ++mt)
            #pragma unroll
            for (int r = 0; r < 4; ++r) {
                int e = eb + mt * 16 + lhi * 4 + r;
                if (e < LEn) {
                    float v = acc[mt][nt][r] + bs + wl * lg_ea[e];
                    float s = v / (1.f + __expf(-v));
                    atomicAdd(&lgacc[(size_t)lg_dst[e] * 128 + col], s);
                }
            }
    }
}

// ---------------- K2: lg finalize + edge LayerNorm ----------------
__global__ __launch_bounds__(256) void k_lg_final_edge_ln(
    const float* __restrict__ lg_x, const float* __restrict__ edge_attr,
    const float* __restrict__ cnt,
    const float* __restrict__ g_edge, const float* __restrict__ beta_edge,
    float* __restrict__ out_lg, float* __restrict__ out_edge, int En)
{
    const int wave = threadIdx.x >> 6;
    const int lane = threadIdx.x & 63;
    const int e = blockIdx.x * 4 + wave;
    if (e >= En) return;
    const size_t base = (size_t)e * 128 + lane * 2;
    float2 accv = *(const float2*)&out_lg[base];
    float2 lgv  = *(const float2*)&lg_x[base];
    float inv = 1.f / fmaxf(cnt[e], 1.f);
    float2 lnew = make_float2(fmaf(accv.x, inv, lgv.x), fmaf(accv.y, inv, lgv.y));
    *(float2*)&out_lg[base] = lnew;
    float2 ea = *(const float2*)&edge_attr[base];
    float t0 = ea.x + lnew.x, t1 = ea.y + lnew.y;
    float s = t0 + t1, sq = t0 * t0 + t1 * t1;
    #pragma unroll
    for (int off = 32; off; off >>= 1) {
        s  += __shfl_xor(s, off);
        sq += __shfl_xor(sq, off);
    }
    float mean = s * (1.f / 128.f);
    float var  = sq * (1.f / 128.f) - mean * mean;
    float r = rsqrtf(var + 1e-5f);
    int j0 = lane * 2;
    float o0 = (t0 - mean) * r * g_edge[j0]     + beta_edge[j0];
    float o1 = (t1 - mean) * r * g_edge[j0 + 1] + beta_edge[j0 + 1];
    *(float2*)&out_edge[base] = make_float2(o0, o1);
}

// ---------------- K3: gate GEMM + gated scatter ----------------
__global__ __launch_bounds__(256) void k_gate_mfma(
    const float* __restrict__ Ein, const short* __restrict__ Wp,
    const float* __restrict__ bg, const int* __restrict__ colidx,
    float* __restrict__ agg, int En)
{
    __shared__ s16x8 B[2048];                 // 32 KB
    const int tid = threadIdx.x;
    #pragma unroll
    for (int i = 0; i < 8; ++i)
        ((float4*)B)[tid + i * 256] = ((const float4*)Wp)[tid + i * 256];
    __syncthreads();

    const int ln = tid & 63, wv = tid >> 6;
    const int l15 = ln & 15, lhi = ln >> 4;
    const int eb = blockIdx.x * 128 + wv * 32;

    const float* rp[2];
    #pragma unroll
    for (int mt = 0; mt < 2; ++mt) {
        int e = eb + mt * 16 + l15;
        rp[mt] = Ein + (size_t)(e < En ? e : En - 1) * 128;
    }

    f32x4 acc[2][8];
    #pragma unroll
    for (int m = 0; m < 2; ++m)
        #pragma unroll
        for (int n = 0; n < 8; ++n) acc[m][n] = (f32x4){0.f, 0.f, 0.f, 0.f};

    #pragma unroll 2
    for (int kt = 0; kt < 4; ++kt) {
        int ko = kt * 32 + lhi * 8;
        s16x8 a[2];
        #pragma unroll
        for (int mt = 0; mt < 2; ++mt) {
            float4 u0 = *(const float4*)(rp[mt] + ko);
            float4 u1 = *(const float4*)(rp[mt] + ko + 4);
            a[mt] = pack8(u0, u1);
        }
        const s16x8* brow = &B[(kt * 4 + lhi) * 128 + l15];
        #pragma unroll
        for (int nt = 0; nt < 8; ++nt) {
            s16x8 b = brow[nt * 16];
            acc[0][nt] = __builtin_amdgcn_mfma_f32_16x16x32_bf16(a[0], b, acc[0][nt], 0, 0, 0);
            acc[1][nt] = __builtin_amdgcn_mfma_f32_16x16x32_bf16(a[1], b, acc[1][nt], 0, 0, 0);
        }
    }

    #pragma unroll
    for (int nt = 0; nt < 8; ++nt) {
        int col = nt * 16 + l15;
        float bs = bg[col];
        #pragma unroll
        for (int mt = 0; mt < 2; ++mt)
            #pragma unroll
            for (int r = 0; r < 4; ++r) {
                int e = eb + mt * 16 + lhi * 4 + r;
                if (e < En) {
                    float g = 1.f / (1.f + __expf(-(acc[mt][nt][r] + bs)));
                    float val = g * Ein[(size_t)e * 128 + col];
                    atomicAdd(&agg[(size_t)colidx[e] * 128 + col], val);
                }
            }
    }
}

// ---------------- K4: atom GEMM + residual + in-register LayerNorm ----------------
__global__ __launch_bounds__(256) void k_atom_mfma(
    const float* __restrict__ x, const float* __restrict__ aggin,
    const short* __restrict__ Wp, const float* __restrict__ ba,
    const float* __restrict__ gn, const float* __restrict__ bn,
    float* __restrict__ out, int Nn)
{
    __shared__ s16x8 B[4096];                 // 64 KB
    const int tid = threadIdx.x;
    #pragma unroll
    for (int i = 0; i < 16; ++i)
        ((float4*)B)[tid + i * 256] = ((const float4*)Wp)[tid + i * 256];
    __syncthreads();

    const int ln = tid & 63, wv = tid >> 6;
    const int l15 = ln & 15, lhi = ln >> 4;
    const int nb = blockIdx.x * 128 + wv * 32;

    const float *xp[2], *ap[2];
    #pragma unroll
    for (int mt = 0; mt < 2; ++mt) {
        int n = nb + mt * 16 + l15;
        size_t nc = (size_t)(n < Nn ? n : Nn - 1) * 128;
        xp[mt] = x + nc;
        ap[mt] = aggin + nc;
    }

    f32x4 acc[2][8];
    #pragma unroll
    for (int m = 0; m < 2; ++m)
        #pragma unroll
        for (int n = 0; n < 8; ++n) acc[m][n] = (f32x4){0.f, 0.f, 0.f, 0.f};

    #pragma unroll 2
    for (int kt = 0; kt < 8; ++kt) {
        int ko = (kt & 3) * 32 + lhi * 8;
        s16x8 a[2];
        #pragma unroll
        for (int mt = 0; mt < 2; ++mt) {
            const float* p = (kt < 4) ? xp[mt] : ap[mt];
            float4 u0 = *(const float4*)(p + ko);
            float4 u1 = *(const float4*)(p + ko + 4);
            a[mt] = pack8(u0, u1);
        }
        const s16x8* brow = &B[(kt * 4 + lhi) * 128 + l15];
        #pragma unroll
        for (int nt = 0; nt < 8; ++nt) {
            s16x8 b = brow[nt * 16];
            acc[0][nt] = __builtin_amdgcn_mfma_f32_16x16x32_bf16(a[0], b, acc[0][nt], 0, 0, 0);
            acc[1][nt] = __builtin_amdgcn_mfma_f32_16x16x32_bf16(a[1], b, acc[1][nt], 0, 0, 0);
        }
    }

    // t = x + silu(acc + ba), in place
    #pragma unroll
    for (int mt = 0; mt < 2; ++mt)
        #pragma unroll
        for (int r = 0; r < 4; ++r) {
            int n = nb + mt * 16 + lhi * 4 + r;
            size_t nr = (size_t)(n < Nn ? n : 0) * 128;
            #pragma unroll
            for (int nt = 0; nt < 8; ++nt) {
                int col = nt * 16 + l15;
                float v = acc[mt][nt][r] + ba[col];
                float h = v / (1.f + __expf(-v));
                acc[mt][nt][r] = x[nr + col] + h;
            }
        }

    // LayerNorm per row: reduce over 16-lane group (xor 1,2,4,8) + 8 nt regs
    #pragma unroll
    for (int mt = 0; mt < 2; ++mt)
        #pragma unroll
        for (int r = 0; r < 4; ++r) {
            float s = 0.f, sq = 0.f;
            #pragma unroll
            for (int nt = 0; nt < 8; ++nt) {
                float t = acc[mt][nt][r];
                s += t; sq += t * t;
            }
            #pragma unroll
            for (int off = 8; off; off >>= 1) {
                s  += __shfl_xor(s, off);
                sq += __shfl_xor(sq, off);
            }
            float mean = s * (1.f / 128.f);
            float var  = sq * (1.f / 128.f) - mean * mean;
            float rstd = rsqrtf(var + 1e-5f);
            int n = nb + mt * 16 + lhi * 4 + r;
            if (n < Nn) {
                #pragma unroll
                for (int nt = 0; nt < 8; ++nt) {
                    int col = nt * 16 + l15;
                    float o = (acc[mt][nt][r] - mean) * rstd * gn[col] + bn[col];
                    out[(size_t)n * 128 + col] = o;
                }
            }
        }
}

extern "C" void kernel_launch(void* const* d_in, const int* in_sizes, int n_in,
                              void* d_out, int out_size, void* d_ws, size_t ws_size,
                              hipStream_t stream) {
    const float* x          = (const float*)d_in[0];
    const float* edge_attr  = (const float*)d_in[1];
    const float* lg_x       = (const float*)d_in[2];
    const float* lg_ea      = (const float*)d_in[3];
    const float* W_line     = (const float*)d_in[4];
    const float* b_line     = (const float*)d_in[5];
    const float* W_gate     = (const float*)d_in[6];
    const float* b_gate     = (const float*)d_in[7];
    const float* W_atom     = (const float*)d_in[8];
    const float* b_atom     = (const float*)d_in[9];
    const float* g_node     = (const float*)d_in[10];
    const float* beta_node  = (const float*)d_in[11];
    const float* g_edge     = (const float*)d_in[12];
    const float* beta_edge  = (const float*)d_in[13];
    const int*   edge_index    = (const int*)d_in[14];
    const int*   lg_edge_index = (const int*)d_in[15];

    const int Nn  = in_sizes[0] / 128;
    const int En  = in_sizes[1] / 128;
    const int LEn = in_sizes[3];

    float* out_x    = (float*)d_out;
    float* out_edge = out_x + (size_t)Nn * 128;
    float* out_lg   = out_edge + (size_t)En * 128;

    short* wp_line = (short*)d_ws;            // 32768 shorts (64 KB)
    short* wp_gate = wp_line + 32768;         // 16384 shorts (32 KB)
    short* wp_atom = wp_gate + 16384;         // 32768 shorts (64 KB)
    float* cnt     = (float*)(wp_atom + 32768);

    const int* lg_src = lg_edge_index;
    const int* lg_dst = lg_edge_index + LEn;
    const int* col    = edge_index + En;

    hipMemsetAsync(out_x,  0, (size_t)Nn * 128 * sizeof(float), stream);
    hipMemsetAsync(out_lg, 0, (size_t)En * 128 * sizeof(float), stream);
    hipMemsetAsync(cnt,    0, (size_t)En * sizeof(float), stream);

    k_pack<<<16, 256, 0, stream>>>(W_line, wp_line, 4096);
    k_pack<<<8,  256, 0, stream>>>(W_gate, wp_gate, 2048);
    k_pack<<<16, 256, 0, stream>>>(W_atom, wp_atom, 4096);
    k_count<<<(LEn + 255) / 256, 256, 0, stream>>>(lg_dst, cnt, LEn);

    k_line_mfma<<<(LEn + 127) / 128, 256, 0, stream>>>(
        lg_x, lg_ea, wp_line, W_line, b_line, lg_src, lg_dst, out_lg, LEn);
    k_lg_final_edge_ln<<<(En + 3) / 4, 256, 0, stream>>>(
        lg_x, edge_attr, cnt, g_edge, beta_edge, out_lg, out_edge, En);
    k_gate_mfma<<<(En + 127) / 128, 256, 0, stream>>>(
        out_edge, wp_gate, b_gate, col, out_x, En);
    k_atom_mfma<<<(Nn + 127) / 128, 256, 0, stream>>>(
        x, out_x, wp_atom, b_atom, g_node, beta_node, out_x, Nn);
}